// Round 5
// baseline (212.732 us; speedup 1.0000x reference)
//
#include <hip/hip_runtime.h>
#include <hip/hip_bf16.h>
#include <cstdint>
#include <cstddef>

typedef short short8 __attribute__((ext_vector_type(8)));
typedef float f32x4 __attribute__((ext_vector_type(4)));

#define NS    2048
#define KPAD  288     // 285 sig channels padded to 288
#define H2    512
#define HID   256
#define WPB   21      // windows per sig workgroup (3 thirds x 189 lanes)
#define SBLK  98      // ceil(2048/21)

// async global->LDS 16B: dst must be the WAVE-UNIFORM base; lane i lands at dst + i*16
__device__ __forceinline__ void gl2lds16(const void* g, void* l) {
    __builtin_amdgcn_global_load_lds(
        (const __attribute__((address_space(1))) void*)g,
        (__attribute__((address_space(3))) void*)l, 16, 0, 0);
}

__device__ __forceinline__ float geluf(float x) {
    return 0.5f * x * (1.0f + erff(x * 0.70710678118654752f));
}

__device__ __forceinline__ f32x4 shfl4(f32x4 v, int d) {
    f32x4 r;
    r[0] = __shfl_xor(v[0], d); r[1] = __shfl_xor(v[1], d);
    r[2] = __shfl_xor(v[2], d); r[3] = __shfl_xor(v[3], d);
    return r;
}

// ---- compile-time necklace-representative table: (i,j,k) -> feat col (45+rank) or -1
struct Tbl3 { short col[729]; };
static constexpr Tbl3 make_tbl3() {
    Tbl3 t{};
    for (int x = 0; x < 729; ++x) t.col[x] = -1;
    int r = 0;
    for (int i = 0; i < 9; ++i)
        for (int j = 0; j < 9; ++j)
            for (int k = 0; k < 9; ++k) {
                bool lt1 = (i < j) || (i == j && (j < k || (j == k && k < i)));
                bool lt2 = (i < k) || (i == k && (j < i || (j == i && k < j)));
                if (lt1 && lt2) { t.col[(i*9+j)*9+k] = (short)(45 + r); ++r; }
            }
    return t;
}
static constexpr Tbl3 TBL3 = make_tbl3();

// ============================================================================
// Signature kernel, 3-way row-split.  UNITS LESSON (r1-r4): WRITE_SIZE is KB;
// 9216 KB == the feats output exactly — there was never any scratch spill.
// Real bottleneck: occupancy (2.3 waves/SIMD, grid-limited) + ds_read latency.
// New shape: 27 lanes/window (each lane owns 3 of the 9 S3 rows -> ~55 live
// VGPRs), 576-thread blocks where each third (3 waves) runs a wave-uniform
// code path for its row subset.  784 blocks x 9 waves = 6.9 waves/SIMD.
// ============================================================================
#define SIG_LOOP(RA,RB,RC) \
    for (int j = 0; j < 60; ++j) { \
        int g = sm59 + j; g = (g > 0) ? g : 0; \
        const float* row = &X[(g - lo) * 8]; \
        const float4 c0 = *(const float4*)(row); \
        const float4 c1 = *(const float4*)(row + 4); \
        const float rs  = row[ioff]; \
        const float dtj = (j == 0) ? 0.0f : DT; \
        const float v0 = dtj; \
        const float v1 = c0.x - prev0, v2 = c0.y - prev1, v3 = c0.z - prev2, v4 = c0.w - prev3; \
        const float v5 = c1.x - prev4, v6 = c1.y - prev5, v7 = c1.z - prev6, v8 = c1.w - prev7; \
        const float vi = (ci == 0) ? dtj : (rs - pscal); \
        const float hh = 0.5f * S1i + vi * (1.0f / 6.0f); \
        { const float ra = S2ra + hh * v##RA; \
          S3a0 += ra*v0; S3a1 += ra*v1; S3a2 += ra*v2; S3a3 += ra*v3; S3a4 += ra*v4; \
          S3a5 += ra*v5; S3a6 += ra*v6; S3a7 += ra*v7; S3a8 += ra*v8; } \
        { const float rb = S2rb + hh * v##RB; \
          S3b0 += rb*v0; S3b1 += rb*v1; S3b2 += rb*v2; S3b3 += rb*v3; S3b4 += rb*v4; \
          S3b5 += rb*v5; S3b6 += rb*v6; S3b7 += rb*v7; S3b8 += rb*v8; } \
        { const float rc = S2rc + hh * v##RC; \
          S3c0 += rc*v0; S3c1 += rc*v1; S3c2 += rc*v2; S3c3 += rc*v3; S3c4 += rc*v4; \
          S3c5 += rc*v5; S3c6 += rc*v6; S3c7 += rc*v7; S3c8 += rc*v8; } \
        const float aa = S1i + 0.5f * vi; \
        S2ra += aa * v##RA; S2rb += aa * v##RB; S2rc += aa * v##RC; \
        S1i += vi; \
        prev0 = c0.x; prev1 = c0.y; prev2 = c0.z; prev3 = c0.w; \
        prev4 = c1.x; prev5 = c1.y; prev6 = c1.z; prev7 = c1.w; \
        pscal = rs; \
    }

#define SIG_ST(RA,RB,RC) \
    if (act) { \
        if ((RA) == 0) S1buf[widx * 9 + ci] = S1i; \
        float* sb = &S2buf[widx * 81 + ci * 9]; \
        sb[RA] = S2ra; sb[RB] = S2rb; sb[RC] = S2rc; \
    }

#define SIG_E2(SL,J2) if (ci < (J2)) { \
    const float val2 = S2r##SL - 0.5f * S1i * s1v##J2; \
    const int col2 = 9 + ci*8 - (ci*(ci-1))/2 + ((J2) - ci - 1); \
    frow[col2] = __float2bfloat16(val2); }

#define SIG_E3(SL,R,K) { const int col3 = TBL3.col[tb + (R)*9 + (K)]; \
    if (col3 >= 0) { \
        const float val3 = S3##SL##K \
            - 0.5f * (S1i * S2w[(R)*9+(K)] + S2r##SL * s1v##K) \
            + S1i * s1v##R * s1v##K * (1.0f/3.0f); \
        frow[col3] = __float2bfloat16(val3); } }

#define SIG_E3R(SL,R) SIG_E3(SL,R,0) SIG_E3(SL,R,1) SIG_E3(SL,R,2) SIG_E3(SL,R,3) \
    SIG_E3(SL,R,4) SIG_E3(SL,R,5) SIG_E3(SL,R,6) SIG_E3(SL,R,7) SIG_E3(SL,R,8)

#define SIG_EMIT(RA,RB,RC) \
    if (act) { \
        if ((RA) == 0) { \
            frow[ci] = __float2bfloat16(S1i); \
            if (ci == 0) { \
                const __hip_bfloat16 z16 = __float2bfloat16(0.0f); \
                frow[285] = z16; frow[286] = z16; frow[287] = z16; \
            } \
        } \
        SIG_E2(a,RA) SIG_E2(b,RB) SIG_E2(c,RC) \
        SIG_E3R(a,RA) SIG_E3R(b,RB) SIG_E3R(c,RC) \
    }

__global__ __launch_bounds__(576) __attribute__((amdgpu_waves_per_eu(1, 6)))
void sig_kernel(const float* __restrict__ x, __hip_bfloat16* __restrict__ feats) {
    __shared__ __align__(16) float X[80 * 8];
    __shared__ float S2buf[WPB * 81];
    __shared__ float S1buf[WPB * 9];

    const int blk = blockIdx.x;
    const int b   = blk / SBLK;
    const int s0  = (blk % SBLK) * WPB;
    const int lo  = (s0 - 59 > 0) ? (s0 - 59) : 0;
    const int hi  = (s0 + WPB - 1 < NS - 1) ? (s0 + WPB - 1) : (NS - 1);
    const int nrow = hi - lo + 1;     // <= 80
    const int tid = threadIdx.x;

    {   // stage x[b, lo..hi, 0..7] -> LDS (row-major [pos][ch])
        const float4* src = (const float4*)(x + ((size_t)b * NS + lo) * 8);
        float4* dst = (float4*)X;
        const int n4 = nrow * 2;
        for (int t = tid; t < n4; t += 576) dst[t] = src[t];
    }
    __syncthreads();

    const int t3    = tid / 192;          // third 0/1/2 -> rows {0,1,2}/{3,4,5}/{6,7,8}; wave-uniform (192 = 3 waves)
    const int lt    = tid - t3 * 192;     // 0..191 (189..191 idle)
    const int widx0 = lt / 9;             // 0..21
    const int ci    = lt - widx0 * 9;     // slab index i in 0..8
    const int s_raw = s0 + widx0;
    const bool act  = (lt < 189) && (s_raw < NS);
    const int widx  = (widx0 < 20) ? widx0 : 20;        // clamp idle lanes into range
    int s = s0 + widx; if (s > NS - 1) s = NS - 1;      // clamp tail

    float S3a0=0.f,S3a1=0.f,S3a2=0.f,S3a3=0.f,S3a4=0.f,S3a5=0.f,S3a6=0.f,S3a7=0.f,S3a8=0.f;
    float S3b0=0.f,S3b1=0.f,S3b2=0.f,S3b3=0.f,S3b4=0.f,S3b5=0.f,S3b6=0.f,S3b7=0.f,S3b8=0.f;
    float S3c0=0.f,S3c1=0.f,S3c2=0.f,S3c3=0.f,S3c4=0.f,S3c5=0.f,S3c6=0.f,S3c7=0.f,S3c8=0.f;
    float S2ra=0.f, S2rb=0.f, S2rc=0.f;
    float S1i = 0.f;
    float prev0=0.f,prev1=0.f,prev2=0.f,prev3=0.f,prev4=0.f,prev5=0.f,prev6=0.f,prev7=0.f;
    float pscal = 0.f;
    const int ioff = (ci > 0) ? (ci - 1) : 0;
    const int sm59 = s - 59;
    const float DT = 1.0f / 59.0f;

    if (t3 == 0)      { SIG_LOOP(0,1,2) }
    else if (t3 == 1) { SIG_LOOP(3,4,5) }
    else              { SIG_LOOP(6,7,8) }

    // cross-lane exchange (once): full S1 and S2 of each window into LDS
    if (t3 == 0)      { SIG_ST(0,1,2) }
    else if (t3 == 1) { SIG_ST(3,4,5) }
    else              { SIG_ST(6,7,8) }
    __syncthreads();

    const float* s1p = &S1buf[widx * 9];
    const float s1v0=s1p[0], s1v1=s1p[1], s1v2=s1p[2], s1v3=s1p[3], s1v4=s1p[4];
    const float s1v5=s1p[5], s1v6=s1p[6], s1v7=s1p[7], s1v8=s1p[8];
    const float* S2w = &S2buf[widx * 81];
    const int tb = ci * 81;
    __hip_bfloat16* frow = feats + (size_t)(b * NS + s) * KPAD;

    if (t3 == 0)      { SIG_EMIT(0,1,2) }
    else if (t3 == 1) { SIG_EMIT(3,4,5) }
    else              { SIG_EMIT(6,7,8) }
}

// ============================================================================
// Weight transpose/cast kernels (tiny)
// ============================================================================
__global__ void convert_w1(const float* __restrict__ w1, __hip_bfloat16* __restrict__ w1T) {
    const int n = blockIdx.x;          // 0..511
    const int k = threadIdx.x;         // 0..287
    const float v = (k < 285) ? w1[(size_t)k * H2 + n] : 0.0f;
    w1T[(size_t)n * KPAD + k] = __float2bfloat16(v);
}
__global__ void convert_w2(const float* __restrict__ w2, __hip_bfloat16* __restrict__ w2T) {
    const int n = blockIdx.x;          // 0..255
    const int k = threadIdx.x;         // 0..511
    w2T[(size_t)n * H2 + k] = __float2bfloat16(w2[(size_t)k * HID + n]);
}

// ============================================================================
// GEMM1: h = LN(GELU(feats @ w1 + b1)) -> bf16.  Block = 64 rows x 512 cols,
// 8 waves, wave tile 64x64, 16x16x32 bf16 MFMA.  (unchanged from r4 —
// awaiting counters now that sig should drop below it in the top-5)
// ============================================================================
#define G1_DECLACC(m) f32x4 acc##m##0 = {0.f,0.f,0.f,0.f}, acc##m##1 = {0.f,0.f,0.f,0.f}, \
                            acc##m##2 = {0.f,0.f,0.f,0.f}, acc##m##3 = {0.f,0.f,0.f,0.f};
#define G1_MFMA(m) { const short8 afr = *(const short8*)(ldsA + ((m)*16 + l16)*32 + quad*8); \
    acc##m##0 = __builtin_amdgcn_mfma_f32_16x16x32_bf16(afr, bfrag0, acc##m##0, 0,0,0); \
    acc##m##1 = __builtin_amdgcn_mfma_f32_16x16x32_bf16(afr, bfrag1, acc##m##1, 0,0,0); \
    acc##m##2 = __builtin_amdgcn_mfma_f32_16x16x32_bf16(afr, bfrag2, acc##m##2, 0,0,0); \
    acc##m##3 = __builtin_amdgcn_mfma_f32_16x16x32_bf16(afr, bfrag3, acc##m##3, 0,0,0); }
#define G1_GELU1(m,n) { \
    acc##m##n[0]=geluf(acc##m##n[0]+bias##n); acc##m##n[1]=geluf(acc##m##n[1]+bias##n); \
    acc##m##n[2]=geluf(acc##m##n[2]+bias##n); acc##m##n[3]=geluf(acc##m##n[3]+bias##n); }
#define G1_GELUR(m) G1_GELU1(m,0) G1_GELU1(m,1) G1_GELU1(m,2) G1_GELU1(m,3)
#define G1_LNS(m) f32x4 psum##m = acc##m##0 + acc##m##1 + acc##m##2 + acc##m##3; \
    f32x4 psq##m = acc##m##0*acc##m##0 + acc##m##1*acc##m##1 + acc##m##2*acc##m##2 + acc##m##3*acc##m##3;
#define G1_STP(m) { const int rrp = (m)*16 + quad*4; \
    lnpart[wave][rrp+0][0]=psum##m[0]; lnpart[wave][rrp+0][1]=psq##m[0]; \
    lnpart[wave][rrp+1][0]=psum##m[1]; lnpart[wave][rrp+1][1]=psq##m[1]; \
    lnpart[wave][rrp+2][0]=psum##m[2]; lnpart[wave][rrp+2][1]=psq##m[2]; \
    lnpart[wave][rrp+3][0]=psum##m[3]; lnpart[wave][rrp+3][1]=psq##m[3]; }
#define G1_LDST(m) f32x4 mu##m; f32x4 rstd##m; { const int rrl = (m)*16 + quad*4; \
    mu##m[0]=lnstat[rrl+0][0]; mu##m[1]=lnstat[rrl+1][0]; mu##m[2]=lnstat[rrl+2][0]; mu##m[3]=lnstat[rrl+3][0]; \
    rstd##m[0]=lnstat[rrl+0][1]; rstd##m[1]=lnstat[rrl+1][1]; rstd##m[2]=lnstat[rrl+2][1]; rstd##m[3]=lnstat[rrl+3][1]; }
#define G1_OUT(m,n) { const int colo = wave*64 + (n)*16 + l16; \
    f32x4 hv = (acc##m##n - mu##m) * rstd##m * gv##n + bv##n; \
    const int rro = (m)*16 + quad*4; \
    hbuf[(size_t)(m0+rro+0)*H2 + colo] = __float2bfloat16(hv[0]); \
    hbuf[(size_t)(m0+rro+1)*H2 + colo] = __float2bfloat16(hv[1]); \
    hbuf[(size_t)(m0+rro+2)*H2 + colo] = __float2bfloat16(hv[2]); \
    hbuf[(size_t)(m0+rro+3)*H2 + colo] = __float2bfloat16(hv[3]); }
#define G1_OUTR(m) G1_OUT(m,0) G1_OUT(m,1) G1_OUT(m,2) G1_OUT(m,3)

__global__ __launch_bounds__(512) __attribute__((amdgpu_waves_per_eu(1, 3)))
void gemm1_kernel(
        const __hip_bfloat16* __restrict__ feats,
        const __hip_bfloat16* __restrict__ w1T,
        const float* __restrict__ b1,
        const float* __restrict__ lng,
        const float* __restrict__ lnb,
        __hip_bfloat16* __restrict__ hbuf) {
    __shared__ __align__(16) __hip_bfloat16 ldsA[64 * 32];
    __shared__ __align__(16) __hip_bfloat16 ldsB[512 * 32];
    __shared__ float lnpart[8][64][2];
    __shared__ float lnstat[64][2];

    const int tid  = threadIdx.x;
    const int wave = tid >> 6;
    const int lane = tid & 63;
    const int quad = lane >> 4;
    const int l16  = lane & 15;
    const int m0   = blockIdx.x * 64;

    G1_DECLACC(0) G1_DECLACC(1) G1_DECLACC(2) G1_DECLACC(3)

#pragma unroll 1
    for (int kt = 0; kt < 9; ++kt) {
        const int K0 = kt * 32;
        if (tid < 256) {               // A tile 64x32: waves 0-3, lane order == LDS order
            const int m = tid >> 2, kc = tid & 3;
            gl2lds16(feats + (size_t)(m0 + m) * KPAD + K0 + kc * 8,
                     (char*)ldsA + (tid & ~63) * 16);
        }
#pragma unroll
        for (int q = 0; q < 4; ++q) {  // B tile 512x32 ([n][k])
            const int chunk = q * 512 + tid;
            const int n = chunk >> 2, kc = chunk & 3;
            gl2lds16(w1T + (size_t)n * KPAD + K0 + kc * 8,
                     (char*)ldsB + (chunk & ~63) * 16);
        }
        __syncthreads();
        const __hip_bfloat16* bbase = ldsB + (wave * 64 + l16) * 32 + quad * 8;
        const short8 bfrag0 = *(const short8*)(bbase);
        const short8 bfrag1 = *(const short8*)(bbase + 16 * 32);
        const short8 bfrag2 = *(const short8*)(bbase + 32 * 32);
        const short8 bfrag3 = *(const short8*)(bbase + 48 * 32);
        G1_MFMA(0) G1_MFMA(1) G1_MFMA(2) G1_MFMA(3)
        __syncthreads();
    }

    // ---- epilogue: bias + exact GELU in place (C frag: row = quad*4+reg, col = l16) ----
    const float bias0 = b1[wave*64 +  0 + l16];
    const float bias1 = b1[wave*64 + 16 + l16];
    const float bias2 = b1[wave*64 + 32 + l16];
    const float bias3 = b1[wave*64 + 48 + l16];
    G1_GELUR(0) G1_GELUR(1) G1_GELUR(2) G1_GELUR(3)

    // LayerNorm: per-row sum/sumsq; reduce over 16 lanes (cols) then 8 waves
    G1_LNS(0) G1_LNS(1) G1_LNS(2) G1_LNS(3)
#pragma unroll
    for (int d = 1; d < 16; d <<= 1) {
        psum0 += shfl4(psum0, d); psq0 += shfl4(psq0, d);
        psum1 += shfl4(psum1, d); psq1 += shfl4(psq1, d);
        psum2 += shfl4(psum2, d); psq2 += shfl4(psq2, d);
        psum3 += shfl4(psum3, d); psq3 += shfl4(psq3, d);
    }
    if (l16 == 0) { G1_STP(0) G1_STP(1) G1_STP(2) G1_STP(3) }
    __syncthreads();
    if (tid < 64) {
        float su = 0.f, sq = 0.f;
#pragma unroll
        for (int w = 0; w < 8; ++w) { su += lnpart[w][tid][0]; sq += lnpart[w][tid][1]; }
        const float mu  = su * (1.0f / 512.0f);
        const float var = sq * (1.0f / 512.0f) - mu * mu;   // population var (ddof=0)
        lnstat[tid][0] = mu;
        lnstat[tid][1] = rsqrtf(var + 1e-5f);
    }
    __syncthreads();
    const float gv0 = lng[wave*64 +  0 + l16], bv0 = lnb[wave*64 +  0 + l16];
    const float gv1 = lng[wave*64 + 16 + l16], bv1 = lnb[wave*64 + 16 + l16];
    const float gv2 = lng[wave*64 + 32 + l16], bv2 = lnb[wave*64 + 32 + l16];
    const float gv3 = lng[wave*64 + 48 + l16], bv3 = lnb[wave*64 + 48 + l16];
    G1_LDST(0) G1_LDST(1) G1_LDST(2) G1_LDST(3)
    G1_OUTR(0) G1_OUTR(1) G1_OUTR(2) G1_OUTR(3)
}

// ============================================================================
// GEMM2: out = h @ w2 + b2 (fp32 out). Block = 64 rows x 256 cols, 8 waves,
// wave tile 64x32, K=512 in 16 steps of 32.  (unchanged from r4)
// ============================================================================
#define G2_DECL(m) f32x4 bcc##m##0 = {0.f,0.f,0.f,0.f}, bcc##m##1 = {0.f,0.f,0.f,0.f};
#define G2_MFMA(m) { const short8 afr = *(const short8*)(ldsA + ((m)*16 + l16)*32 + quad*8); \
    bcc##m##0 = __builtin_amdgcn_mfma_f32_16x16x32_bf16(afr, bfr0, bcc##m##0, 0,0,0); \
    bcc##m##1 = __builtin_amdgcn_mfma_f32_16x16x32_bf16(afr, bfr1, bcc##m##1, 0,0,0); }
#define G2_OUT(m) { const int rro = (m)*16 + quad*4; \
    out[(size_t)(m0+rro+0)*HID + c0i] = bcc##m##0[0] + bb0; \
    out[(size_t)(m0+rro+1)*HID + c0i] = bcc##m##0[1] + bb0; \
    out[(size_t)(m0+rro+2)*HID + c0i] = bcc##m##0[2] + bb0; \
    out[(size_t)(m0+rro+3)*HID + c0i] = bcc##m##0[3] + bb0; \
    out[(size_t)(m0+rro+0)*HID + c1i] = bcc##m##1[0] + bb1; \
    out[(size_t)(m0+rro+1)*HID + c1i] = bcc##m##1[1] + bb1; \
    out[(size_t)(m0+rro+2)*HID + c1i] = bcc##m##1[2] + bb1; \
    out[(size_t)(m0+rro+3)*HID + c1i] = bcc##m##1[3] + bb1; }

__global__ __launch_bounds__(512) __attribute__((amdgpu_waves_per_eu(1, 3)))
void gemm2_kernel(
        const __hip_bfloat16* __restrict__ hbuf,
        const __hip_bfloat16* __restrict__ w2T,
        const float* __restrict__ b2,
        float* __restrict__ out) {
    __shared__ __align__(16) __hip_bfloat16 ldsA[64 * 32];
    __shared__ __align__(16) __hip_bfloat16 ldsB[256 * 32];
    const int tid  = threadIdx.x;
    const int wave = tid >> 6;
    const int lane = tid & 63;
    const int quad = lane >> 4;
    const int l16  = lane & 15;
    const int m0   = blockIdx.x * 64;

    G2_DECL(0) G2_DECL(1) G2_DECL(2) G2_DECL(3)

#pragma unroll 1
    for (int kt = 0; kt < 16; ++kt) {
        const int K0 = kt * 32;
        if (tid < 256) {
            const int m = tid >> 2, kc = tid & 3;
            gl2lds16(hbuf + (size_t)(m0 + m) * H2 + K0 + kc * 8,
                     (char*)ldsA + (tid & ~63) * 16);
        }
#pragma unroll
        for (int q = 0; q < 2; ++q) {
            const int chunk = q * 512 + tid;
            const int n = chunk >> 2, kc = chunk & 3;
            gl2lds16(w2T + (size_t)n * H2 + K0 + kc * 8,
                     (char*)ldsB + (chunk & ~63) * 16);
        }
        __syncthreads();
        const __hip_bfloat16* bbase = ldsB + (wave * 32 + l16) * 32 + quad * 8;
        const short8 bfr0 = *(const short8*)(bbase);
        const short8 bfr1 = *(const short8*)(bbase + 16 * 32);
        G2_MFMA(0) G2_MFMA(1) G2_MFMA(2) G2_MFMA(3)
        __syncthreads();
    }
    const float bb0 = b2[wave*32 +  0 + l16];
    const float bb1 = b2[wave*32 + 16 + l16];
    const int c0i = wave*32 +  0 + l16;
    const int c1i = wave*32 + 16 + l16;
    G2_OUT(0) G2_OUT(1) G2_OUT(2) G2_OUT(3)
}

// ============================================================================
extern "C" void kernel_launch(void* const* d_in, const int* in_sizes, int n_in,
                              void* d_out, int out_size, void* d_ws, size_t ws_size,
                              hipStream_t stream) {
    const float* x   = (const float*)d_in[0];
    const float* w1  = (const float*)d_in[1];
    const float* b1  = (const float*)d_in[2];
    const float* lng = (const float*)d_in[3];
    const float* lnb = (const float*)d_in[4];
    const float* w2  = (const float*)d_in[5];
    const float* b2  = (const float*)d_in[6];
    float* out = (float*)d_out;

    char* ws = (char*)d_ws;
    __hip_bfloat16* feats = (__hip_bfloat16*)(ws);                       // 16384*288*2 = 9437184
    __hip_bfloat16* hbuf  = (__hip_bfloat16*)(ws + 9437184);             // 16384*512*2 = 16777216
    __hip_bfloat16* w1T   = (__hip_bfloat16*)(ws + 9437184 + 16777216);  // 512*288*2  = 294912
    __hip_bfloat16* w2T   = (__hip_bfloat16*)(ws + 9437184 + 16777216 + 294912); // 256*512*2

    convert_w1<<<dim3(512), dim3(288), 0, stream>>>(w1, w1T);
    convert_w2<<<dim3(256), dim3(512), 0, stream>>>(w2, w2T);
    sig_kernel<<<dim3(8 * SBLK), dim3(576), 0, stream>>>(x, feats);
    gemm1_kernel<<<dim3(16384 / 64), dim3(512), 0, stream>>>(feats, w1T, b1, lng, lnb, hbuf);
    gemm2_kernel<<<dim3(16384 / 64), dim3(512), 0, stream>>>(hbuf, w2T, b2, out);
}

// Round 6
// 171.808 us; speedup vs baseline: 1.2382x; 1.2382x over previous
//
#include <hip/hip_runtime.h>
#include <hip/hip_bf16.h>
#include <cstdint>
#include <cstddef>

typedef short short8 __attribute__((ext_vector_type(8)));
typedef float f32x4 __attribute__((ext_vector_type(4)));

#define NS    2048
#define KPAD  288     // 285 sig channels padded to 288
#define H2    512
#define HID   256
#define WPB   21      // windows per sig workgroup (3 thirds x 189 lanes)
#define SBLK  98      // ceil(2048/21)

// async global->LDS 16B: dst must be the WAVE-UNIFORM base; lane i lands at dst + i*16
__device__ __forceinline__ void gl2lds16(const void* g, void* l) {
    __builtin_amdgcn_global_load_lds(
        (const __attribute__((address_space(1))) void*)g,
        (__attribute__((address_space(3))) void*)l, 16, 0, 0);
}

__device__ __forceinline__ float geluf(float x) {
    return 0.5f * x * (1.0f + erff(x * 0.70710678118654752f));
}

__device__ __forceinline__ f32x4 shfl4(f32x4 v, int d) {
    f32x4 r;
    r[0] = __shfl_xor(v[0], d); r[1] = __shfl_xor(v[1], d);
    r[2] = __shfl_xor(v[2], d); r[3] = __shfl_xor(v[3], d);
    return r;
}

// ---- compile-time necklace-representative table: (i,j,k) -> feat col (45+rank) or -1
struct Tbl3 { short col[729]; };
static constexpr Tbl3 make_tbl3() {
    Tbl3 t{};
    for (int x = 0; x < 729; ++x) t.col[x] = -1;
    int r = 0;
    for (int i = 0; i < 9; ++i)
        for (int j = 0; j < 9; ++j)
            for (int k = 0; k < 9; ++k) {
                bool lt1 = (i < j) || (i == j && (j < k || (j == k && k < i)));
                bool lt2 = (i < k) || (i == k && (j < i || (j == i && k < j)));
                if (lt1 && lt2) { t.col[(i*9+j)*9+k] = (short)(45 + r); ++r; }
            }
    return t;
}
static constexpr Tbl3 TBL3 = make_tbl3();

// ============================================================================
// Signature kernel, 3-way row-split (r5 skeleton) with r6 fixes:
//  - D[] = precomputed increment rows in LDS (kills per-step subs/prev/pscal)
//  - explicit register prefetch pipeline + unroll 1 (r5 regression: full
//    unroll x3 paths ~50KB -> I$ thrash; VALUBusy stuck 36%)
//  - live set ~55 VGPR, under the ~72 arch cap -> no AGPR shuttle tax
// ============================================================================
#define SIG_STEP(RA,RB,RC) { \
    const float hh = 0.5f * S1i + vi * (1.0f / 6.0f); \
    { const float ra = S2ra + hh * v##RA; \
      S3a0 += ra*v0; S3a1 += ra*v1; S3a2 += ra*v2; S3a3 += ra*v3; S3a4 += ra*v4; \
      S3a5 += ra*v5; S3a6 += ra*v6; S3a7 += ra*v7; S3a8 += ra*v8; } \
    { const float rb = S2rb + hh * v##RB; \
      S3b0 += rb*v0; S3b1 += rb*v1; S3b2 += rb*v2; S3b3 += rb*v3; S3b4 += rb*v4; \
      S3b5 += rb*v5; S3b6 += rb*v6; S3b7 += rb*v7; S3b8 += rb*v8; } \
    { const float rc = S2rc + hh * v##RC; \
      S3c0 += rc*v0; S3c1 += rc*v1; S3c2 += rc*v2; S3c3 += rc*v3; S3c4 += rc*v4; \
      S3c5 += rc*v5; S3c6 += rc*v6; S3c7 += rc*v7; S3c8 += rc*v8; } \
    const float aa = S1i + 0.5f * vi; \
    S2ra += aa * v##RA; S2rb += aa * v##RB; S2rc += aa * v##RC; \
    S1i += vi; }

#define SIG_MAIN(RA,RB,RC) { \
    /* j = 0: increments are the ABSOLUTE first point (diff w/ prepend-0) */ \
    const float* xr = &X[(g0 - lo) * 8]; \
    const float4 e0p = *(const float4*)xr; \
    const float4 e1p = *(const float4*)(xr + 4); \
    const float rabs = xr[ioff]; \
    { const float v0 = 0.f; \
      const float v1 = e0p.x, v2 = e0p.y, v3 = e0p.z, v4 = e0p.w; \
      const float v5 = e1p.x, v6 = e1p.y, v7 = e1p.z, v8 = e1p.w; \
      const float vi = (ci == 0) ? 0.f : rabs; \
      SIG_STEP(RA,RB,RC) } \
    /* j = 1..59: prefetch-pipelined over precomputed diff rows D */ \
    int gn = sm59 + 1; gn = (gn > 0) ? gn : 0; \
    const float* dp = &D[(gn - lo) * 8]; \
    float4 d0 = *(const float4*)dp; \
    float4 d1 = *(const float4*)(dp + 4); \
    float rn = dp[ioff]; \
    _Pragma("unroll 1") \
    for (int j = 1; j < 60; ++j) { \
      const float4 e0 = d0; const float4 e1 = d1; const float rs = rn; \
      int g2 = sm59 + j + 1; g2 = (g2 > 0) ? g2 : 0; \
      const float* dn = &D[(g2 - lo) * 8]; \
      d0 = *(const float4*)dn; d1 = *(const float4*)(dn + 4); rn = dn[ioff]; \
      const float v0 = DT; \
      const float v1 = e0.x, v2 = e0.y, v3 = e0.z, v4 = e0.w; \
      const float v5 = e1.x, v6 = e1.y, v7 = e1.z, v8 = e1.w; \
      const float vi = (ci == 0) ? DT : rs; \
      SIG_STEP(RA,RB,RC) \
    } }

#define SIG_ST(RA,RB,RC) \
    if (act) { \
        if ((RA) == 0) S1buf[widx * 9 + ci] = S1i; \
        float* sb = &S2buf[widx * 81 + ci * 9]; \
        sb[RA] = S2ra; sb[RB] = S2rb; sb[RC] = S2rc; \
    }

#define SIG_E2(SL,J2) if (ci < (J2)) { \
    const float val2 = S2r##SL - 0.5f * S1i * s1v##J2; \
    const int col2 = 9 + ci*8 - (ci*(ci-1))/2 + ((J2) - ci - 1); \
    frow[col2] = __float2bfloat16(val2); }

#define SIG_E3(SL,R,K) { const int col3 = TBL3.col[tb + (R)*9 + (K)]; \
    if (col3 >= 0) { \
        const float val3 = S3##SL##K \
            - 0.5f * (S1i * S2w[(R)*9+(K)] + S2r##SL * s1v##K) \
            + S1i * s1v##R * s1v##K * (1.0f/3.0f); \
        frow[col3] = __float2bfloat16(val3); } }

#define SIG_E3R(SL,R) SIG_E3(SL,R,0) SIG_E3(SL,R,1) SIG_E3(SL,R,2) SIG_E3(SL,R,3) \
    SIG_E3(SL,R,4) SIG_E3(SL,R,5) SIG_E3(SL,R,6) SIG_E3(SL,R,7) SIG_E3(SL,R,8)

#define SIG_EMIT(RA,RB,RC) \
    if (act) { \
        if ((RA) == 0) { \
            frow[ci] = __float2bfloat16(S1i); \
            if (ci == 0) { \
                const __hip_bfloat16 z16 = __float2bfloat16(0.0f); \
                frow[285] = z16; frow[286] = z16; frow[287] = z16; \
            } \
        } \
        SIG_E2(a,RA) SIG_E2(b,RB) SIG_E2(c,RC) \
        SIG_E3R(a,RA) SIG_E3R(b,RB) SIG_E3R(c,RC) \
    }

__global__ __launch_bounds__(576) __attribute__((amdgpu_waves_per_eu(1, 6)))
void sig_kernel(const float* __restrict__ x, __hip_bfloat16* __restrict__ feats) {
    __shared__ __align__(16) float X[82 * 8];
    __shared__ __align__(16) float D[82 * 8];
    __shared__ float S2buf[WPB * 81];
    __shared__ float S1buf[WPB * 9];

    const int blk = blockIdx.x;
    const int b   = blk / SBLK;
    const int s0  = (blk % SBLK) * WPB;
    const int lo  = (s0 - 59 > 0) ? (s0 - 59) : 0;
    const int hi  = (s0 + WPB - 1 < NS - 1) ? (s0 + WPB - 1) : (NS - 1);
    const int nrow = hi - lo + 1;     // <= 80
    const int tid = threadIdx.x;

    {   // stage x[b, lo..hi, 0..7] -> LDS X (row-major [pos][ch])
        const float4* src = (const float4*)(x + ((size_t)b * NS + lo) * 8);
        float4* dst = (float4*)X;
        const int n4 = nrow * 2;
        for (int t = tid; t < n4; t += 576) dst[t] = src[t];
    }
    __syncthreads();
    {   // D[r] = X[r] - X[r-1]; D[0] = 0 (left-clamp => zero increment);
        // rows >= nrow zero-filled (j=59 prefetch may touch row nrow)
        const float4* X4 = (const float4*)X;
        float4* D4 = (float4*)D;
        for (int t = tid; t < 164; t += 576) {
            const int r = t >> 1;
            float4 dv = {0.f, 0.f, 0.f, 0.f};
            if (r > 0 && r < nrow) {
                const float4 a = X4[t], bb = X4[t - 2];
                dv.x = a.x - bb.x; dv.y = a.y - bb.y; dv.z = a.z - bb.z; dv.w = a.w - bb.w;
            }
            D4[t] = dv;
        }
    }
    __syncthreads();

    const int t3    = tid / 192;          // third 0/1/2 (wave-uniform: 192 = 3 waves)
    const int lt    = tid - t3 * 192;     // 0..191 (189..191 idle)
    const int widx0 = lt / 9;             // 0..21
    const int ci    = lt - widx0 * 9;     // slab index i in 0..8
    const int s_raw = s0 + widx0;
    const bool act  = (lt < 189) && (s_raw < NS);
    const int widx  = (widx0 < 20) ? widx0 : 20;
    int s = s0 + widx; if (s > NS - 1) s = NS - 1;

    float S3a0=0.f,S3a1=0.f,S3a2=0.f,S3a3=0.f,S3a4=0.f,S3a5=0.f,S3a6=0.f,S3a7=0.f,S3a8=0.f;
    float S3b0=0.f,S3b1=0.f,S3b2=0.f,S3b3=0.f,S3b4=0.f,S3b5=0.f,S3b6=0.f,S3b7=0.f,S3b8=0.f;
    float S3c0=0.f,S3c1=0.f,S3c2=0.f,S3c3=0.f,S3c4=0.f,S3c5=0.f,S3c6=0.f,S3c7=0.f,S3c8=0.f;
    float S2ra=0.f, S2rb=0.f, S2rc=0.f;
    float S1i = 0.f;
    const int ioff = (ci > 0) ? (ci - 1) : 0;
    const int sm59 = s - 59;
    const int g0   = (sm59 > 0) ? sm59 : 0;
    const float DT = 1.0f / 59.0f;

    if (t3 == 0)      { SIG_MAIN(0,1,2) }
    else if (t3 == 1) { SIG_MAIN(3,4,5) }
    else              { SIG_MAIN(6,7,8) }

    if (t3 == 0)      { SIG_ST(0,1,2) }
    else if (t3 == 1) { SIG_ST(3,4,5) }
    else              { SIG_ST(6,7,8) }
    __syncthreads();

    const float* s1p = &S1buf[widx * 9];
    const float s1v0=s1p[0], s1v1=s1p[1], s1v2=s1p[2], s1v3=s1p[3], s1v4=s1p[4];
    const float s1v5=s1p[5], s1v6=s1p[6], s1v7=s1p[7], s1v8=s1p[8];
    const float* S2w = &S2buf[widx * 81];
    const int tb = ci * 81;
    __hip_bfloat16* frow = feats + (size_t)(b * NS + s) * KPAD;

    if (t3 == 0)      { SIG_EMIT(0,1,2) }
    else if (t3 == 1) { SIG_EMIT(3,4,5) }
    else              { SIG_EMIT(6,7,8) }
}

// ============================================================================
// Weight transpose/cast kernels (tiny)
// ============================================================================
__global__ void convert_w1(const float* __restrict__ w1, __hip_bfloat16* __restrict__ w1T) {
    const int n = blockIdx.x;          // 0..511
    const int k = threadIdx.x;         // 0..287
    const float v = (k < 285) ? w1[(size_t)k * H2 + n] : 0.0f;
    w1T[(size_t)n * KPAD + k] = __float2bfloat16(v);
}
__global__ void convert_w2(const float* __restrict__ w2, __hip_bfloat16* __restrict__ w2T) {
    const int n = blockIdx.x;          // 0..255
    const int k = threadIdx.x;         // 0..511
    w2T[(size_t)n * H2 + k] = __float2bfloat16(w2[(size_t)k * HID + n]);
}

// ============================================================================
// GEMM1: h = LN(GELU(feats @ w1 + b1)) -> bf16.  M-tile 32 (r6: was 64 ->
// only 256 blocks = 1 block/CU with barrier drain fully exposed; now 512
// blocks = 2 blocks/CU = 4 waves/SIMD).  8 waves, wave tile 32x64.
// ============================================================================
#define G1_DECLACC(m) f32x4 acc##m##0 = {0.f,0.f,0.f,0.f}, acc##m##1 = {0.f,0.f,0.f,0.f}, \
                            acc##m##2 = {0.f,0.f,0.f,0.f}, acc##m##3 = {0.f,0.f,0.f,0.f};
#define G1_MFMA(m) { const short8 afr = *(const short8*)(ldsA + ((m)*16 + l16)*32 + quad*8); \
    acc##m##0 = __builtin_amdgcn_mfma_f32_16x16x32_bf16(afr, bfrag0, acc##m##0, 0,0,0); \
    acc##m##1 = __builtin_amdgcn_mfma_f32_16x16x32_bf16(afr, bfrag1, acc##m##1, 0,0,0); \
    acc##m##2 = __builtin_amdgcn_mfma_f32_16x16x32_bf16(afr, bfrag2, acc##m##2, 0,0,0); \
    acc##m##3 = __builtin_amdgcn_mfma_f32_16x16x32_bf16(afr, bfrag3, acc##m##3, 0,0,0); }
#define G1_GELU1(m,n) { \
    acc##m##n[0]=geluf(acc##m##n[0]+bias##n); acc##m##n[1]=geluf(acc##m##n[1]+bias##n); \
    acc##m##n[2]=geluf(acc##m##n[2]+bias##n); acc##m##n[3]=geluf(acc##m##n[3]+bias##n); }
#define G1_GELUR(m) G1_GELU1(m,0) G1_GELU1(m,1) G1_GELU1(m,2) G1_GELU1(m,3)
#define G1_LNS(m) f32x4 psum##m = acc##m##0 + acc##m##1 + acc##m##2 + acc##m##3; \
    f32x4 psq##m = acc##m##0*acc##m##0 + acc##m##1*acc##m##1 + acc##m##2*acc##m##2 + acc##m##3*acc##m##3;
#define G1_STP(m) { const int rrp = (m)*16 + quad*4; \
    lnpart[wave][rrp+0][0]=psum##m[0]; lnpart[wave][rrp+0][1]=psq##m[0]; \
    lnpart[wave][rrp+1][0]=psum##m[1]; lnpart[wave][rrp+1][1]=psq##m[1]; \
    lnpart[wave][rrp+2][0]=psum##m[2]; lnpart[wave][rrp+2][1]=psq##m[2]; \
    lnpart[wave][rrp+3][0]=psum##m[3]; lnpart[wave][rrp+3][1]=psq##m[3]; }
#define G1_LDST(m) f32x4 mu##m; f32x4 rstd##m; { const int rrl = (m)*16 + quad*4; \
    mu##m[0]=lnstat[rrl+0][0]; mu##m[1]=lnstat[rrl+1][0]; mu##m[2]=lnstat[rrl+2][0]; mu##m[3]=lnstat[rrl+3][0]; \
    rstd##m[0]=lnstat[rrl+0][1]; rstd##m[1]=lnstat[rrl+1][1]; rstd##m[2]=lnstat[rrl+2][1]; rstd##m[3]=lnstat[rrl+3][1]; }
#define G1_OUT(m,n) { const int colo = wave*64 + (n)*16 + l16; \
    f32x4 hv = (acc##m##n - mu##m) * rstd##m * gv##n + bv##n; \
    const int rro = (m)*16 + quad*4; \
    hbuf[(size_t)(m0+rro+0)*H2 + colo] = __float2bfloat16(hv[0]); \
    hbuf[(size_t)(m0+rro+1)*H2 + colo] = __float2bfloat16(hv[1]); \
    hbuf[(size_t)(m0+rro+2)*H2 + colo] = __float2bfloat16(hv[2]); \
    hbuf[(size_t)(m0+rro+3)*H2 + colo] = __float2bfloat16(hv[3]); }
#define G1_OUTR(m) G1_OUT(m,0) G1_OUT(m,1) G1_OUT(m,2) G1_OUT(m,3)

__global__ __launch_bounds__(512) __attribute__((amdgpu_waves_per_eu(1, 4)))
void gemm1_kernel(
        const __hip_bfloat16* __restrict__ feats,
        const __hip_bfloat16* __restrict__ w1T,
        const float* __restrict__ b1,
        const float* __restrict__ lng,
        const float* __restrict__ lnb,
        __hip_bfloat16* __restrict__ hbuf) {
    __shared__ __align__(16) __hip_bfloat16 ldsA[32 * 32];
    __shared__ __align__(16) __hip_bfloat16 ldsB[512 * 32];
    __shared__ float lnpart[8][32][2];
    __shared__ float lnstat[32][2];

    const int tid  = threadIdx.x;
    const int wave = tid >> 6;
    const int lane = tid & 63;
    const int quad = lane >> 4;
    const int l16  = lane & 15;
    const int m0   = blockIdx.x * 32;

    G1_DECLACC(0) G1_DECLACC(1)

#pragma unroll 1
    for (int kt = 0; kt < 9; ++kt) {
        const int K0 = kt * 32;
        if (tid < 128) {               // A tile 32x32: waves 0-1, lane order == LDS order
            const int m = tid >> 2, kc = tid & 3;
            gl2lds16(feats + (size_t)(m0 + m) * KPAD + K0 + kc * 8,
                     (char*)ldsA + (tid & ~63) * 16);
        }
#pragma unroll
        for (int q = 0; q < 4; ++q) {  // B tile 512x32 ([n][k])
            const int chunk = q * 512 + tid;
            const int n = chunk >> 2, kc = chunk & 3;
            gl2lds16(w1T + (size_t)n * KPAD + K0 + kc * 8,
                     (char*)ldsB + (chunk & ~63) * 16);
        }
        __syncthreads();
        const __hip_bfloat16* bbase = ldsB + (wave * 64 + l16) * 32 + quad * 8;
        const short8 bfrag0 = *(const short8*)(bbase);
        const short8 bfrag1 = *(const short8*)(bbase + 16 * 32);
        const short8 bfrag2 = *(const short8*)(bbase + 32 * 32);
        const short8 bfrag3 = *(const short8*)(bbase + 48 * 32);
        G1_MFMA(0) G1_MFMA(1)
        __syncthreads();
    }

    // ---- epilogue: bias + exact GELU in place (C frag: row = quad*4+reg, col = l16) ----
    const float bias0 = b1[wave*64 +  0 + l16];
    const float bias1 = b1[wave*64 + 16 + l16];
    const float bias2 = b1[wave*64 + 32 + l16];
    const float bias3 = b1[wave*64 + 48 + l16];
    G1_GELUR(0) G1_GELUR(1)

    // LayerNorm: per-row sum/sumsq; reduce over 16 lanes (cols) then 8 waves
    G1_LNS(0) G1_LNS(1)
#pragma unroll
    for (int d = 1; d < 16; d <<= 1) {
        psum0 += shfl4(psum0, d); psq0 += shfl4(psq0, d);
        psum1 += shfl4(psum1, d); psq1 += shfl4(psq1, d);
    }
    if (l16 == 0) { G1_STP(0) G1_STP(1) }
    __syncthreads();
    if (tid < 32) {
        float su = 0.f, sq = 0.f;
#pragma unroll
        for (int w = 0; w < 8; ++w) { su += lnpart[w][tid][0]; sq += lnpart[w][tid][1]; }
        const float mu  = su * (1.0f / 512.0f);
        const float var = sq * (1.0f / 512.0f) - mu * mu;   // population var (ddof=0)
        lnstat[tid][0] = mu;
        lnstat[tid][1] = rsqrtf(var + 1e-5f);
    }
    __syncthreads();
    const float gv0 = lng[wave*64 +  0 + l16], bv0 = lnb[wave*64 +  0 + l16];
    const float gv1 = lng[wave*64 + 16 + l16], bv1 = lnb[wave*64 + 16 + l16];
    const float gv2 = lng[wave*64 + 32 + l16], bv2 = lnb[wave*64 + 32 + l16];
    const float gv3 = lng[wave*64 + 48 + l16], bv3 = lnb[wave*64 + 48 + l16];
    G1_LDST(0) G1_LDST(1)
    G1_OUTR(0) G1_OUTR(1)
}

// ============================================================================
// GEMM2: out = h @ w2 + b2 (fp32 out).  M-tile 32 -> 512 blocks (2/CU),
// 8 waves, wave tile 32x32, K=512 in 16 steps of 32.
// ============================================================================
#define G2_DECL(m) f32x4 bcc##m##0 = {0.f,0.f,0.f,0.f}, bcc##m##1 = {0.f,0.f,0.f,0.f};
#define G2_MFMA(m) { const short8 afr = *(const short8*)(ldsA + ((m)*16 + l16)*32 + quad*8); \
    bcc##m##0 = __builtin_amdgcn_mfma_f32_16x16x32_bf16(afr, bfr0, bcc##m##0, 0,0,0); \
    bcc##m##1 = __builtin_amdgcn_mfma_f32_16x16x32_bf16(afr, bfr1, bcc##m##1, 0,0,0); }
#define G2_OUT(m) { const int rro = (m)*16 + quad*4; \
    out[(size_t)(m0+rro+0)*HID + c0i] = bcc##m##0[0] + bb0; \
    out[(size_t)(m0+rro+1)*HID + c0i] = bcc##m##0[1] + bb0; \
    out[(size_t)(m0+rro+2)*HID + c0i] = bcc##m##0[2] + bb0; \
    out[(size_t)(m0+rro+3)*HID + c0i] = bcc##m##0[3] + bb0; \
    out[(size_t)(m0+rro+0)*HID + c1i] = bcc##m##1[0] + bb1; \
    out[(size_t)(m0+rro+1)*HID + c1i] = bcc##m##1[1] + bb1; \
    out[(size_t)(m0+rro+2)*HID + c1i] = bcc##m##1[2] + bb1; \
    out[(size_t)(m0+rro+3)*HID + c1i] = bcc##m##1[3] + bb1; }

__global__ __launch_bounds__(512) __attribute__((amdgpu_waves_per_eu(1, 4)))
void gemm2_kernel(
        const __hip_bfloat16* __restrict__ hbuf,
        const __hip_bfloat16* __restrict__ w2T,
        const float* __restrict__ b2,
        float* __restrict__ out) {
    __shared__ __align__(16) __hip_bfloat16 ldsA[32 * 32];
    __shared__ __align__(16) __hip_bfloat16 ldsB[256 * 32];
    const int tid  = threadIdx.x;
    const int wave = tid >> 6;
    const int lane = tid & 63;
    const int quad = lane >> 4;
    const int l16  = lane & 15;
    const int m0   = blockIdx.x * 32;

    G2_DECL(0) G2_DECL(1)

#pragma unroll 1
    for (int kt = 0; kt < 16; ++kt) {
        const int K0 = kt * 32;
        if (tid < 128) {
            const int m = tid >> 2, kc = tid & 3;
            gl2lds16(hbuf + (size_t)(m0 + m) * H2 + K0 + kc * 8,
                     (char*)ldsA + (tid & ~63) * 16);
        }
#pragma unroll
        for (int q = 0; q < 2; ++q) {
            const int chunk = q * 512 + tid;
            const int n = chunk >> 2, kc = chunk & 3;
            gl2lds16(w2T + (size_t)n * H2 + K0 + kc * 8,
                     (char*)ldsB + (chunk & ~63) * 16);
        }
        __syncthreads();
        const __hip_bfloat16* bbase = ldsB + (wave * 32 + l16) * 32 + quad * 8;
        const short8 bfr0 = *(const short8*)(bbase);
        const short8 bfr1 = *(const short8*)(bbase + 16 * 32);
        G2_MFMA(0) G2_MFMA(1)
        __syncthreads();
    }
    const float bb0 = b2[wave*32 +  0 + l16];
    const float bb1 = b2[wave*32 + 16 + l16];
    const int c0i = wave*32 +  0 + l16;
    const int c1i = wave*32 + 16 + l16;
    G2_OUT(0) G2_OUT(1)
}

// ============================================================================
extern "C" void kernel_launch(void* const* d_in, const int* in_sizes, int n_in,
                              void* d_out, int out_size, void* d_ws, size_t ws_size,
                              hipStream_t stream) {
    const float* x   = (const float*)d_in[0];
    const float* w1  = (const float*)d_in[1];
    const float* b1  = (const float*)d_in[2];
    const float* lng = (const float*)d_in[3];
    const float* lnb = (const float*)d_in[4];
    const float* w2  = (const float*)d_in[5];
    const float* b2  = (const float*)d_in[6];
    float* out = (float*)d_out;

    char* ws = (char*)d_ws;
    __hip_bfloat16* feats = (__hip_bfloat16*)(ws);                       // 16384*288*2 = 9437184
    __hip_bfloat16* hbuf  = (__hip_bfloat16*)(ws + 9437184);             // 16384*512*2 = 16777216
    __hip_bfloat16* w1T   = (__hip_bfloat16*)(ws + 9437184 + 16777216);  // 512*288*2  = 294912
    __hip_bfloat16* w2T   = (__hip_bfloat16*)(ws + 9437184 + 16777216 + 294912); // 256*512*2

    convert_w1<<<dim3(512), dim3(288), 0, stream>>>(w1, w1T);
    convert_w2<<<dim3(256), dim3(512), 0, stream>>>(w2, w2T);
    sig_kernel<<<dim3(8 * SBLK), dim3(576), 0, stream>>>(x, feats);
    gemm1_kernel<<<dim3(16384 / 32), dim3(512), 0, stream>>>(feats, w1T, b1, lng, lnb, hbuf);
    gemm2_kernel<<<dim3(16384 / 32), dim3(512), 0, stream>>>(hbuf, w2T, b2, out);
}

// Round 7
// 163.660 us; speedup vs baseline: 1.2998x; 1.0498x over previous
//
#include <hip/hip_runtime.h>
#include <hip/hip_bf16.h>
#include <cstdint>
#include <cstddef>

typedef short short8 __attribute__((ext_vector_type(8)));
typedef float f32x4 __attribute__((ext_vector_type(4)));
typedef float f32x2 __attribute__((ext_vector_type(2)));

#define NS    2048
#define KPAD  288
#define H2    512
#define HID   256
#define WPB   7       // windows per sig workgroup (192 thr = 3 waves = 3 thirds)
#define SBLK  293     // ceil(2048/7)

#define MFMA(a,b,c) __builtin_amdgcn_mfma_f32_16x16x32_bf16((a),(b),(c),0,0,0)

__device__ __forceinline__ void gl2lds16(const void* g, void* l) {
    __builtin_amdgcn_global_load_lds(
        (const __attribute__((address_space(1))) void*)g,
        (__attribute__((address_space(3))) void*)l, 16, 0, 0);
}
__device__ __forceinline__ float geluf(float x) {
    return 0.5f * x * (1.0f + erff(x * 0.70710678118654752f));
}
__device__ __forceinline__ f32x4 shfl4(f32x4 v, int d) {
    f32x4 r;
    r[0] = __shfl_xor(v[0], d); r[1] = __shfl_xor(v[1], d);
    r[2] = __shfl_xor(v[2], d); r[3] = __shfl_xor(v[3], d);
    return r;
}

struct Tbl3 { short col[729]; };
static constexpr Tbl3 make_tbl3() {
    Tbl3 t{};
    for (int x = 0; x < 729; ++x) t.col[x] = -1;
    int r = 0;
    for (int i = 0; i < 9; ++i)
        for (int j = 0; j < 9; ++j)
            for (int k = 0; k < 9; ++k) {
                bool lt1 = (i < j) || (i == j && (j < k || (j == k && k < i)));
                bool lt2 = (i < k) || (i == k && (j < i || (j == i && k < j)));
                if (lt1 && lt2) { t.col[(i*9+j)*9+k] = (short)(45 + r); ++r; }
            }
    return t;
}
static constexpr Tbl3 TBL3 = make_tbl3();

// ============================================================================
// sig: 3 thirds (1 wave each), WPB=7.  r6 lesson: LDS pipe is the wall;
// here we halve VALU issue via v_pk_fma (f32x2) and kill per-step clamp via
// 59-row zero-padded D + pointer increment.
// ============================================================================
#define SIG_STEP(VA_,VB_,VC_) { \
    const float hh = 0.5f * S1i + vi * (1.0f/6.0f); \
    const float ra = S2ra + hh * (VA_); \
    const float rb = S2rb + hh * (VB_); \
    const float rc = S2rc + hh * (VC_); \
    const f32x2 ra2 = {ra, ra}, rb2 = {rb, rb}, rc2 = {rc, rc}; \
    S3sa += ra * v0; S3pa0 += ra2*vp0; S3pa1 += ra2*vp1; S3pa2 += ra2*vp2; S3pa3 += ra2*vp3; \
    S3sb += rb * v0; S3pb0 += rb2*vp0; S3pb1 += rb2*vp1; S3pb2 += rb2*vp2; S3pb3 += rb2*vp3; \
    S3sc += rc * v0; S3pc0 += rc2*vp0; S3pc1 += rc2*vp1; S3pc2 += rc2*vp2; S3pc3 += rc2*vp3; \
    const float aa = S1i + 0.5f * vi; \
    S2ra += aa * (VA_); S2rb += aa * (VB_); S2rc += aa * (VC_); \
    S1i += vi; }

#define SIG_MAIN(VA_,VB_,VC_) { \
    { const float* xr = &X[(g0 - lo) * 8]; \
      const float4 e0 = *(const float4*)xr; \
      const float4 e1 = *(const float4*)(xr + 4); \
      const float rs = xr[ioff]; \
      const float v0 = 0.0f; \
      const f32x2 vp0 = {e0.x, e0.y}, vp1 = {e0.z, e0.w}, vp2 = {e1.x, e1.y}, vp3 = {e1.z, e1.w}; \
      const float vi = (ci == 0) ? 0.0f : rs; \
      SIG_STEP(VA_,VB_,VC_) } \
    const float* pd = &PD[(sm59 + 1 - lo + 59) * 8]; \
    float4 d0 = *(const float4*)pd; \
    float4 d1 = *(const float4*)(pd + 4); \
    float rn = pd[ioff]; \
    _Pragma("unroll 2") \
    for (int j = 1; j < 60; ++j) { \
      const float4 e0 = d0; const float4 e1 = d1; const float rs = rn; \
      pd += 8; \
      d0 = *(const float4*)pd; d1 = *(const float4*)(pd + 4); rn = pd[ioff]; \
      const float v0 = DT; \
      const f32x2 vp0 = {e0.x, e0.y}, vp1 = {e0.z, e0.w}, vp2 = {e1.x, e1.y}, vp3 = {e1.z, e1.w}; \
      const float vi = (ci == 0) ? DT : rs; \
      SIG_STEP(VA_,VB_,VC_) \
    } }

#define SIG_ST(RA,RB,RC) \
    if (act) { \
        if ((RA) == 0) S1buf[widx * 9 + ci] = S1i; \
        float* sb = &S2buf[widx * 81 + ci * 9]; \
        sb[RA] = S2ra; sb[RB] = S2rb; sb[RC] = S2rc; \
    }

#define S3EL0(SL) S3s##SL
#define S3EL1(SL) S3p##SL##0[0]
#define S3EL2(SL) S3p##SL##0[1]
#define S3EL3(SL) S3p##SL##1[0]
#define S3EL4(SL) S3p##SL##1[1]
#define S3EL5(SL) S3p##SL##2[0]
#define S3EL6(SL) S3p##SL##2[1]
#define S3EL7(SL) S3p##SL##3[0]
#define S3EL8(SL) S3p##SL##3[1]

#define SIG_E2(SL,J2) if (ci < (J2)) { \
    const float val2 = S2r##SL - 0.5f * S1i * s1v##J2; \
    const int col2 = 9 + ci*8 - (ci*(ci-1))/2 + ((J2) - ci - 1); \
    frow[col2] = __float2bfloat16(val2); }

#define SIG_E3(SL,R,K) { const int col3 = TBL3.col[tb + (R)*9 + (K)]; \
    if (col3 >= 0) { \
        const float val3 = S3EL##K(SL) \
            - 0.5f * (S1i * S2w[(R)*9+(K)] + S2r##SL * s1v##K) \
            + S1i * s1v##R * s1v##K * (1.0f/3.0f); \
        frow[col3] = __float2bfloat16(val3); } }

#define SIG_E3R(SL,R) SIG_E3(SL,R,0) SIG_E3(SL,R,1) SIG_E3(SL,R,2) SIG_E3(SL,R,3) \
    SIG_E3(SL,R,4) SIG_E3(SL,R,5) SIG_E3(SL,R,6) SIG_E3(SL,R,7) SIG_E3(SL,R,8)

#define SIG_EMIT(RA,RB,RC) \
    if (act) { \
        if ((RA) == 0) { \
            frow[ci] = __float2bfloat16(S1i); \
            if (ci == 0) { \
                const __hip_bfloat16 z16 = __float2bfloat16(0.0f); \
                frow[285] = z16; frow[286] = z16; frow[287] = z16; \
            } \
        } \
        SIG_E2(a,RA) SIG_E2(b,RB) SIG_E2(c,RC) \
        SIG_E3R(a,RA) SIG_E3R(b,RB) SIG_E3R(c,RC) \
    }

__global__ __launch_bounds__(192) __attribute__((amdgpu_waves_per_eu(1, 6)))
void sig_kernel(const float* __restrict__ x, __hip_bfloat16* __restrict__ feats) {
    __shared__ __align__(16) float X[66 * 8];
    __shared__ __align__(16) float PD[126 * 8];   // rows 0..58 zero pad, 59+r = x[lo+r]-x[lo+r-1]
    __shared__ float S2buf[WPB * 81];
    __shared__ float S1buf[WPB * 9];

    const int blk = blockIdx.x;
    const int b   = blk / SBLK;
    const int s0  = (blk % SBLK) * WPB;
    const int lo  = (s0 - 59 > 0) ? (s0 - 59) : 0;
    const int hi  = (s0 + WPB - 1 < NS - 1) ? (s0 + WPB - 1) : (NS - 1);
    const int nrow = hi - lo + 1;     // <= 66
    const int tid = threadIdx.x;

    {   // stage x rows
        const float4* src = (const float4*)(x + ((size_t)b * NS + lo) * 8);
        float4* X4 = (float4*)X;
        const int n4 = nrow * 2;
        for (int t = tid; t < n4; t += 192) X4[t] = src[t];
    }
    __syncthreads();
    {   // build padded diff rows
        const float4* X4 = (const float4*)X;
        float4* PD4 = (float4*)PD;
        for (int t = tid; t < 252; t += 192) {
            const int p = t >> 1;         // padded row
            const int r = p - 59;         // diff row
            float4 dv = {0.f, 0.f, 0.f, 0.f};
            if (r > 0 && r < nrow) {
                const float4 a = X4[t - 118], bb = X4[t - 120];
                dv.x = a.x - bb.x; dv.y = a.y - bb.y; dv.z = a.z - bb.z; dv.w = a.w - bb.w;
            }
            PD4[t] = dv;
        }
    }
    __syncthreads();

    const int t3    = tid >> 6;           // third (wave-uniform): rows {0,1,2}/{3,4,5}/{6,7,8}
    const int lt    = tid & 63;
    const int widx0 = lt / 9;             // 0..7 (lane 63 idle)
    const int ci    = lt - widx0 * 9;     // slab index 0..8
    const bool act  = (lt < 63) && (s0 + widx0 < NS);
    const int widx  = (widx0 < WPB - 1) ? widx0 : WPB - 1;
    int s = s0 + widx; if (s > NS - 1) s = NS - 1;

    float S3sa=0.f, S3sb=0.f, S3sc=0.f;
    f32x2 S3pa0={0.f,0.f},S3pa1={0.f,0.f},S3pa2={0.f,0.f},S3pa3={0.f,0.f};
    f32x2 S3pb0={0.f,0.f},S3pb1={0.f,0.f},S3pb2={0.f,0.f},S3pb3={0.f,0.f};
    f32x2 S3pc0={0.f,0.f},S3pc1={0.f,0.f},S3pc2={0.f,0.f},S3pc3={0.f,0.f};
    float S2ra=0.f, S2rb=0.f, S2rc=0.f;
    float S1i = 0.f;
    const int ioff = (ci > 0) ? (ci - 1) : 0;
    const int sm59 = s - 59;
    const int g0   = (sm59 > 0) ? sm59 : 0;
    const float DT = 1.0f / 59.0f;

    if (t3 == 0)      { SIG_MAIN(v0,   e0.x, e0.y) }
    else if (t3 == 1) { SIG_MAIN(e0.z, e0.w, e1.x) }
    else              { SIG_MAIN(e1.y, e1.z, e1.w) }

    if (t3 == 0)      { SIG_ST(0,1,2) }
    else if (t3 == 1) { SIG_ST(3,4,5) }
    else              { SIG_ST(6,7,8) }
    __syncthreads();

    const float* s1p = &S1buf[widx * 9];
    const float s1v0=s1p[0], s1v1=s1p[1], s1v2=s1p[2], s1v3=s1p[3], s1v4=s1p[4];
    const float s1v5=s1p[5], s1v6=s1p[6], s1v7=s1p[7], s1v8=s1p[8];
    const float* S2w = &S2buf[widx * 81];
    const int tb = ci * 81;
    __hip_bfloat16* frow = feats + (size_t)(b * NS + s) * KPAD;

    if (t3 == 0)      { SIG_EMIT(0,1,2) }
    else if (t3 == 1) { SIG_EMIT(3,4,5) }
    else              { SIG_EMIT(6,7,8) }
}

// ============================================================================
// Weight prep
// ============================================================================
__global__ void convert_w1(const float* __restrict__ w1, __hip_bfloat16* __restrict__ w1T) {
    const int n = blockIdx.x;          // 0..511
    const int k = threadIdx.x;         // 0..287
    const float v = (k < 285) ? w1[(size_t)k * H2 + n] : 0.0f;
    w1T[(size_t)n * KPAD + k] = __float2bfloat16(v);
}
// w2g[n][k] = g_k * w2[k][n]; gw[n] = sum_k g_k w2[k][n]; cvec[n] = sum_k b_k w2[k][n] + b2[n]
__global__ void convert_w2g(const float* __restrict__ w2, const float* __restrict__ lng,
                            const float* __restrict__ lnb, const float* __restrict__ b2,
                            __hip_bfloat16* __restrict__ w2g, float* __restrict__ gw,
                            float* __restrict__ cvec) {
    const int n = blockIdx.x, k = threadIdx.x;
    const float wv = w2[(size_t)k * HID + n];
    const float a = lng[k] * wv;
    const float c = lnb[k] * wv;
    w2g[(size_t)n * H2 + k] = __float2bfloat16(a);
    float ra = a, rc = c;
#pragma unroll
    for (int d = 1; d < 64; d <<= 1) { ra += __shfl_xor(ra, d); rc += __shfl_xor(rc, d); }
    __shared__ float r1[8], r2[8];
    const int wv_ = k >> 6, ln = k & 63;
    if (ln == 0) { r1[wv_] = ra; r2[wv_] = rc; }
    __syncthreads();
    if (k == 0) {
        float sa = 0.f, sc = 0.f;
#pragma unroll
        for (int i = 0; i < 8; ++i) { sa += r1[i]; sc += r2[i]; }
        gw[n] = sa; cvec[n] = sc + b2[n];
    }
}

// ============================================================================
// m97-shape GEMM core: 128x128 tile, 256 thr / 4 waves, wave tile 64x64.
// ============================================================================
#define GDECL \
    f32x4 acc00={0,0,0,0},acc01={0,0,0,0},acc02={0,0,0,0},acc03={0,0,0,0}; \
    f32x4 acc10={0,0,0,0},acc11={0,0,0,0},acc12={0,0,0,0},acc13={0,0,0,0}; \
    f32x4 acc20={0,0,0,0},acc21={0,0,0,0},acc22={0,0,0,0},acc23={0,0,0,0}; \
    f32x4 acc30={0,0,0,0},acc31={0,0,0,0},acc32={0,0,0,0},acc33={0,0,0,0};

#define GMROW(mf) { const short8 av = *(const short8*)(abase + (mf)*512); \
    acc##mf##0 = MFMA(av, b0v, acc##mf##0); acc##mf##1 = MFMA(av, b1v, acc##mf##1); \
    acc##mf##2 = MFMA(av, b2v, acc##mf##2); acc##mf##3 = MFMA(av, b3v, acc##mf##3); }

#define GEMM_KLOOP(APTR, BPTR, KD, KSTEPS) \
    _Pragma("unroll 1") \
    for (int kt = 0; kt < (KSTEPS); ++kt) { \
        const int K0 = kt * 32; \
        { int c = tid; \
          gl2lds16((APTR) + (size_t)(m0 + (c>>2))*(KD) + K0 + (c&3)*8, (char*)ldsA + (c & ~63)*16); \
          gl2lds16((BPTR) + (size_t)(n0 + (c>>2))*(KD) + K0 + (c&3)*8, (char*)ldsB + (c & ~63)*16); \
          c = tid + 256; \
          gl2lds16((APTR) + (size_t)(m0 + (c>>2))*(KD) + K0 + (c&3)*8, (char*)ldsA + (c & ~63)*16); \
          gl2lds16((BPTR) + (size_t)(n0 + (c>>2))*(KD) + K0 + (c&3)*8, (char*)ldsB + (c & ~63)*16); } \
        __syncthreads(); \
        const __hip_bfloat16* abase = ldsA + (mh + l16)*32 + quad*8; \
        const __hip_bfloat16* bbase = ldsB + (nh + l16)*32 + quad*8; \
        const short8 b0v = *(const short8*)(bbase); \
        const short8 b1v = *(const short8*)(bbase + 512); \
        const short8 b2v = *(const short8*)(bbase + 1024); \
        const short8 b3v = *(const short8*)(bbase + 1536); \
        GMROW(0) GMROW(1) GMROW(2) GMROW(3) \
        __syncthreads(); \
    }

// GEMM1: h1 = GELU(feats @ w1 + b1) -> bf16, plus per-row (sum, sumsq) atomics.
#define G1EP(mf,nf) { \
    const int colv = n0 + nh + (nf)*16 + l16; \
    const float bv = bias[colv]; \
    f32x4 e; \
    e[0] = geluf(acc##mf##nf[0] + bv); e[1] = geluf(acc##mf##nf[1] + bv); \
    e[2] = geluf(acc##mf##nf[2] + bv); e[3] = geluf(acc##mf##nf[3] + bv); \
    const int rrow = m0 + mh + (mf)*16 + quad*4; \
    h1[(size_t)(rrow+0)*H2 + colv] = __float2bfloat16(e[0]); \
    h1[(size_t)(rrow+1)*H2 + colv] = __float2bfloat16(e[1]); \
    h1[(size_t)(rrow+2)*H2 + colv] = __float2bfloat16(e[2]); \
    h1[(size_t)(rrow+3)*H2 + colv] = __float2bfloat16(e[3]); \
    sum##mf += e; sq##mf += e*e; }

#define G1RED(mf) { \
    f32x4 s = sum##mf, q = sq##mf; \
    s += shfl4(s,1); q += shfl4(q,1); s += shfl4(s,2); q += shfl4(q,2); \
    s += shfl4(s,4); q += shfl4(q,4); s += shfl4(s,8); q += shfl4(q,8); \
    if (l16 == 0) { const int rrow = m0 + mh + (mf)*16 + quad*4; \
        atomicAdd(&stats[2*(rrow+0)],   s[0]); atomicAdd(&stats[2*(rrow+0)+1], q[0]); \
        atomicAdd(&stats[2*(rrow+1)],   s[1]); atomicAdd(&stats[2*(rrow+1)+1], q[1]); \
        atomicAdd(&stats[2*(rrow+2)],   s[2]); atomicAdd(&stats[2*(rrow+2)+1], q[2]); \
        atomicAdd(&stats[2*(rrow+3)],   s[3]); atomicAdd(&stats[2*(rrow+3)+1], q[3]); } }

__global__ __launch_bounds__(256) __attribute__((amdgpu_waves_per_eu(1, 4)))
void gemm1_kernel(const __hip_bfloat16* __restrict__ feats,
                  const __hip_bfloat16* __restrict__ w1T,
                  const float* __restrict__ bias,
                  __hip_bfloat16* __restrict__ h1,
                  float* __restrict__ stats) {
    __shared__ __align__(16) __hip_bfloat16 ldsA[128 * 32];
    __shared__ __align__(16) __hip_bfloat16 ldsB[128 * 32];
    const int tid  = threadIdx.x;
    const int wave = tid >> 6;
    const int lane = tid & 63;
    const int quad = lane >> 4;
    const int l16  = lane & 15;
    const int mh   = (wave >> 1) * 64;
    const int nh   = (wave & 1) * 64;
    const int m0   = blockIdx.x * 128;
    const int n0   = blockIdx.y * 128;
    GDECL
    GEMM_KLOOP(feats, w1T, KPAD, 9)
    f32x4 sum0={0,0,0,0},sum1={0,0,0,0},sum2={0,0,0,0},sum3={0,0,0,0};
    f32x4 sq0={0,0,0,0},sq1={0,0,0,0},sq2={0,0,0,0},sq3={0,0,0,0};
    G1EP(0,0) G1EP(0,1) G1EP(0,2) G1EP(0,3)
    G1EP(1,0) G1EP(1,1) G1EP(1,2) G1EP(1,3)
    G1EP(2,0) G1EP(2,1) G1EP(2,2) G1EP(2,3)
    G1EP(3,0) G1EP(3,1) G1EP(3,2) G1EP(3,3)
    G1RED(0) G1RED(1) G1RED(2) G1RED(3)
}

// GEMM2: out = rstd_m*(h1 @ w2g - mu_m*gw[n]) + cvec[n]  (LN folded)
#define STATR(r) { const float su = stats[2*(rrow+(r))]; const float qu = stats[2*(rrow+(r))+1]; \
    const float m_ = su * (1.0f/512.0f); const float v_ = qu * (1.0f/512.0f) - m_*m_; \
    muv[r] = m_; rsv[r] = rsqrtf(v_ + 1e-5f); }

#define G2C(mf,nf) { const int colv = n0 + nh + (nf)*16 + l16; \
    const float g_ = gw[colv], c_ = cvec[colv]; \
    out[(size_t)(rrow+0)*HID + colv] = rsv[0]*(acc##mf##nf[0] - muv[0]*g_) + c_; \
    out[(size_t)(rrow+1)*HID + colv] = rsv[1]*(acc##mf##nf[1] - muv[1]*g_) + c_; \
    out[(size_t)(rrow+2)*HID + colv] = rsv[2]*(acc##mf##nf[2] - muv[2]*g_) + c_; \
    out[(size_t)(rrow+3)*HID + colv] = rsv[3]*(acc##mf##nf[3] - muv[3]*g_) + c_; }

#define G2EP(mf) { const int rrow = m0 + mh + (mf)*16 + quad*4; \
    f32x4 muv, rsv; \
    STATR(0) STATR(1) STATR(2) STATR(3) \
    G2C(mf,0) G2C(mf,1) G2C(mf,2) G2C(mf,3) }

__global__ __launch_bounds__(256) __attribute__((amdgpu_waves_per_eu(1, 4)))
void gemm2_kernel(const __hip_bfloat16* __restrict__ h1,
                  const __hip_bfloat16* __restrict__ w2g,
                  const float* __restrict__ stats,
                  const float* __restrict__ gw,
                  const float* __restrict__ cvec,
                  float* __restrict__ out) {
    __shared__ __align__(16) __hip_bfloat16 ldsA[128 * 32];
    __shared__ __align__(16) __hip_bfloat16 ldsB[128 * 32];
    const int tid  = threadIdx.x;
    const int wave = tid >> 6;
    const int lane = tid & 63;
    const int quad = lane >> 4;
    const int l16  = lane & 15;
    const int mh   = (wave >> 1) * 64;
    const int nh   = (wave & 1) * 64;
    const int m0   = blockIdx.x * 128;
    const int n0   = blockIdx.y * 128;
    GDECL
    GEMM_KLOOP(h1, w2g, H2, 16)
    G2EP(0) G2EP(1) G2EP(2) G2EP(3)
}

// ============================================================================
extern "C" void kernel_launch(void* const* d_in, const int* in_sizes, int n_in,
                              void* d_out, int out_size, void* d_ws, size_t ws_size,
                              hipStream_t stream) {
    const float* x   = (const float*)d_in[0];
    const float* w1  = (const float*)d_in[1];
    const float* b1  = (const float*)d_in[2];
    const float* lng = (const float*)d_in[3];
    const float* lnb = (const float*)d_in[4];
    const float* w2  = (const float*)d_in[5];
    const float* b2  = (const float*)d_in[6];
    float* out = (float*)d_out;

    char* ws = (char*)d_ws;
    __hip_bfloat16* feats = (__hip_bfloat16*)(ws);                        // 9437184
    __hip_bfloat16* h1    = (__hip_bfloat16*)(ws + 9437184);              // 16777216
    __hip_bfloat16* w1T   = (__hip_bfloat16*)(ws + 26214400);             // 294912
    __hip_bfloat16* w2g   = (__hip_bfloat16*)(ws + 26509312);             // 262144
    float*          gw    = (float*)(ws + 26771456);                      // 4096
    float*          cvec  = (float*)(ws + 26775552);                      // 4096
    float*          stats = (float*)(ws + 26779648);                      // 131072

    hipMemsetAsync(stats, 0, 16384 * 2 * sizeof(float), stream);
    convert_w1<<<dim3(512), dim3(288), 0, stream>>>(w1, w1T);
    convert_w2g<<<dim3(256), dim3(512), 0, stream>>>(w2, lng, lnb, b2, w2g, gw, cvec);
    sig_kernel<<<dim3(8 * SBLK), dim3(192), 0, stream>>>(x, feats);
    gemm1_kernel<<<dim3(128, 4), dim3(256), 0, stream>>>(feats, w1T, b1, h1, stats);
    gemm2_kernel<<<dim3(128, 2), dim3(256), 0, stream>>>(h1, w2g, stats, gw, cvec, out);
}